// Round 3
// baseline (274.788 us; speedup 1.0000x reference)
//
#include <hip/hip_runtime.h>

// TNNCell scan: B=4096 chains, T=512 steps, 16 lanes/chain, 4 chains/wave.
// grid = 1024 blocks x 64 threads -> 1024 waves = 1 wave/SIMD (all parallelism).
//
// R3 changes vs R2 (which was VALU-issue bound, VALUBusy 67%):
//  - x double-buffered in REGISTERS: step t+1's 7 ds_reads issue before step t's
//    compute; the lgkmcnt wait retires behind ~100 VALU ops (no in-step stall).
//  - store executed by ALL lanes (lanes 4-15 are exact replicas writing the
//    same value to the same address) -> no per-step exec-mask save/restore.
//  - clip via v_med3_f32; gS factoring trims the temp-diff block.

template <int CTRL>
__device__ __forceinline__ float dppadd(float v) {
  int x = __builtin_amdgcn_update_dpp(0, __float_as_int(v), CTRL, 0xF, 0xF, true);
  return v + __int_as_float(x);
}
#define DPP_XOR1 0xB1   // quad_perm [1,0,3,2]
#define DPP_XOR2 0x4E   // quad_perm [2,3,0,1]
#define DPP_ROR4 0x124  // row_ror:4
#define DPP_ROR8 0x128  // row_ror:8

__global__ __launch_bounds__(64, 1) void tnn_scan(
    const float* __restrict__ in,    // (4096, 512, 7)
    const float* __restrict__ caps,  // (1, 4)
    const float* __restrict__ Wg,    // (11, 15)
    const float* __restrict__ bg,    // (15)
    const float* __restrict__ Wp1,   // (11, 16)
    const float* __restrict__ bp1,   // (16)
    const float* __restrict__ Wp2,   // (16, 4)
    const float* __restrict__ bp2,   // (4)
    float* __restrict__ out)         // (4096, 512, 4)
{
  __shared__ float xb[2][4][449];

  const int lane = threadIdx.x;
  const int grp  = lane >> 4;
  const int u    = lane & 15;
  const int ur   = u & 3;

  const int elem = (int)blockIdx.x * 4 + grp;

  // ---- per-lane weight columns ----
  const int ug = (u < 15) ? u : 14;
  const float wg0 = Wg[0*15+ug], wg1 = Wg[1*15+ug], wg2 = Wg[2*15+ug],
              wg3 = Wg[3*15+ug], wg4 = Wg[4*15+ug], wg5 = Wg[5*15+ug],
              wg6 = Wg[6*15+ug], wg7 = Wg[7*15+ug], wg8 = Wg[8*15+ug],
              wg9 = Wg[9*15+ug], wg10 = Wg[10*15+ug];
  const float bgc = bg[ug];
  const float wp0 = Wp1[0*16+u], wp1 = Wp1[1*16+u], wp2 = Wp1[2*16+u],
              wp3 = Wp1[3*16+u], wp4 = Wp1[4*16+u], wp5 = Wp1[5*16+u],
              wp6 = Wp1[6*16+u], wp7 = Wp1[7*16+u], wp8 = Wp1[8*16+u],
              wp9 = Wp1[9*16+u], wp10 = Wp1[10*16+u];
  const float bhc = bp1[u];
  const float w20 = Wp2[u*4+0], w21 = Wp2[u*4+1], w22 = Wp2[u*4+2], w23 = Wp2[u*4+3];

  const float b20 = bp2[0], b21 = bp2[1], b22 = bp2[2], b23 = bp2[3];
  const float LN10 = 2.302585092994046f;
  const float kc0 = 0.5f * __expf(caps[0] * LN10);
  const float kc1 = 0.5f * __expf(caps[1] * LN10);
  const float kc2 = 0.5f * __expf(caps[2] * LN10);
  const float kc3 = 0.5f * __expf(caps[3] * LN10);

  // conduct pair (pi,pj) for conduct index u
  const unsigned long long IPACK = 0x4433222111100000ULL;
  const unsigned long long JPACK = 0x5554543543254321ULL;
  const int pi = (int)((IPACK >> (4 * u)) & 15);
  const int pj = (int)((JPACK >> (4 * u)) & 15);
  const float is0 = (pi == 0) ? 1.f : 0.f, is1 = (pi == 1) ? 1.f : 0.f,
              is2 = (pi == 2) ? 1.f : 0.f, is3 = (pi == 3) ? 1.f : 0.f;
  const float tj1 = (pj == 1) ? 1.f : 0.f, tj2 = (pj == 2) ? 1.f : 0.f,
              tj3 = (pj == 3) ? 1.f : 0.f, tj4 = (pj == 4) ? 1.f : 0.f,
              tj5 = (pj == 5) ? 1.f : 0.f;

  float s0 = 0.f, s1 = 0.f, s2 = 0.f, s3 = 0.f;

  const float* inblk = in + (size_t)((int)blockIdx.x * 4) * 3584;
  float* op = out + (size_t)elem * 2048 + ur;   // all 16 lanes store (4 dup each addr)

  float stg[4][7];
  auto LOADC = [&](int cc) {
    #pragma unroll
    for (int e = 0; e < 4; ++e)
      #pragma unroll
      for (int k = 0; k < 7; ++k)
        stg[e][k] = inblk[(size_t)e * 3584 + cc * 448 + k * 64 + lane];
  };
  auto WRITEC = [&](int bb) {
    #pragma unroll
    for (int e = 0; e < 4; ++e)
      #pragma unroll
      for (int k = 0; k < 7; ++k)
        xb[bb][e][k * 64 + lane] = stg[e][k];
  };

  float xA[7], xB[7];

  auto STEP = [&](int t, const float* __restrict__ x) {
    const float x0 = x[0], x1 = x[1], x2 = x[2], x3 = x[3],
                x4 = x[4], x5 = x[5], x6 = x[6];

    float zgx = fmaf(x0, wg0, fmaf(x1, wg1, fmaf(x2, wg2, fmaf(x3, wg3,
                fmaf(x4, wg4, fmaf(x5, wg9, fmaf(x6, wg10, bgc)))))));
    float zhx = fmaf(x0, wp0, fmaf(x1, wp1, fmaf(x2, wp2, fmaf(x3, wp3,
                fmaf(x4, wp4, fmaf(x5, wp9, fmaf(x6, wp10, bhc)))))));
    const float txx = fmaf(tj4, x5, tj5 * x6);

    const float zg = fmaf(s0, wg5, fmaf(s1, wg6, fmaf(s2, wg7, fmaf(s3, wg8, zgx))));
    const float zh = fmaf(s0, wp5, fmaf(s1, wp6, fmaf(s2, wp7, fmaf(s3, wp8, zhx))));

    const float g = __fdividef(1.0f, 1.0f + __expf(-zg));
    const float h = 1.0f - 2.0f * __fdividef(1.0f, 1.0f + __expf(2.0f * zh));

    float p0 = h * w20, p1 = h * w21, p2 = h * w22, p3 = h * w23;

    const float sjp = fmaf(tj1, s1, fmaf(tj2, s2, tj3 * s3));
    const float Si  = fmaf(is0, s0, fmaf(is1, s1, fmaf(is2, s2, is3 * s3)));
    const float gS  = g * Si;
    const float Tj  = sjp + txx;
    const float ci  = fmaf(g, Tj, -gS);   // g*(Tj - Si)
    const float cj  = fmaf(-g, sjp, gS);  // g*(Si - sjp)
    float t0 = is0 * ci;
    float t1 = fmaf(is1, ci, tj1 * cj);
    float t2 = fmaf(is2, ci, tj2 * cj);
    float t3 = fmaf(is3, ci, tj3 * cj);

    // 16-lane all-reduce of 8 values, pure DPP, 8-way interleaved
    p0 = dppadd<DPP_XOR1>(p0); p1 = dppadd<DPP_XOR1>(p1);
    p2 = dppadd<DPP_XOR1>(p2); p3 = dppadd<DPP_XOR1>(p3);
    t0 = dppadd<DPP_XOR1>(t0); t1 = dppadd<DPP_XOR1>(t1);
    t2 = dppadd<DPP_XOR1>(t2); t3 = dppadd<DPP_XOR1>(t3);
    p0 = dppadd<DPP_XOR2>(p0); p1 = dppadd<DPP_XOR2>(p1);
    p2 = dppadd<DPP_XOR2>(p2); p3 = dppadd<DPP_XOR2>(p3);
    t0 = dppadd<DPP_XOR2>(t0); t1 = dppadd<DPP_XOR2>(t1);
    t2 = dppadd<DPP_XOR2>(t2); t3 = dppadd<DPP_XOR2>(t3);
    p0 = dppadd<DPP_ROR4>(p0); p1 = dppadd<DPP_ROR4>(p1);
    p2 = dppadd<DPP_ROR4>(p2); p3 = dppadd<DPP_ROR4>(p3);
    t0 = dppadd<DPP_ROR4>(t0); t1 = dppadd<DPP_ROR4>(t1);
    t2 = dppadd<DPP_ROR4>(t2); t3 = dppadd<DPP_ROR4>(t3);
    p0 = dppadd<DPP_ROR8>(p0); p1 = dppadd<DPP_ROR8>(p1);
    p2 = dppadd<DPP_ROR8>(p2); p3 = dppadd<DPP_ROR8>(p3);
    t0 = dppadd<DPP_ROR8>(t0); t1 = dppadd<DPP_ROR8>(t1);
    t2 = dppadd<DPP_ROR8>(t2); t3 = dppadd<DPP_ROR8>(t3);

    // emit prev state; all lanes store (replicas write identical values)
    const float sout = (ur == 0) ? s0 : (ur == 1) ? s1 : (ur == 2) ? s2 : s3;
    op[t * 4] = sout;

    const float pl0 = fabsf(p0 + b20);
    const float pl1 = fabsf(p1 + b21);
    const float pl2 = fabsf(p2 + b22);
    const float pl3 = fabsf(p3 + b23);
    s0 = __builtin_amdgcn_fmed3f(fmaf(kc0, t0 + pl0, s0), -1.0f, 5.0f);
    s1 = __builtin_amdgcn_fmed3f(fmaf(kc1, t1 + pl1, s1), -1.0f, 5.0f);
    s2 = __builtin_amdgcn_fmed3f(fmaf(kc2, t2 + pl2, s2), -1.0f, 5.0f);
    s3 = __builtin_amdgcn_fmed3f(fmaf(kc3, t3 + pl3, s3), -1.0f, 5.0f);
  };

  LOADC(0);
  WRITEC(0);
  {  // preload first step
    const float* xr = &xb[0][grp][0];
    #pragma unroll
    for (int k = 0; k < 7; ++k) xA[k] = xr[k];
  }

  #pragma unroll 1
  for (int c = 0; c < 8; ++c) {
    if (c < 7) LOADC(c + 1);          // global prefetch, 64 steps of slack
    const int cb = c & 1;

    #pragma unroll 3
    for (int tin = 0; tin < 63; ++tin) {
      { // issue next step's LDS reads before this step's compute
        const float* xr = &xb[cb][grp][(tin + 1) * 7];
        #pragma unroll
        for (int k = 0; k < 7; ++k) xB[k] = xr[k];
      }
      STEP(c * 64 + tin, xA);
      #pragma unroll
      for (int k = 0; k < 7; ++k) xA[k] = xB[k];
    }
    STEP(c * 64 + 63, xA);

    if (c < 7) {
      WRITEC((c + 1) & 1);            // commit prefetched chunk
      const float* xr = &xb[(c + 1) & 1][grp][0];
      #pragma unroll
      for (int k = 0; k < 7; ++k) xA[k] = xr[k];   // preload next chunk step 0
    }
  }
}

extern "C" void kernel_launch(void* const* d_in, const int* in_sizes, int n_in,
                              void* d_out, int out_size, void* d_ws, size_t ws_size,
                              hipStream_t stream) {
  const float* in   = (const float*)d_in[0];
  const float* caps = (const float*)d_in[1];
  const float* Wg   = (const float*)d_in[2];
  const float* bg   = (const float*)d_in[3];
  const float* Wp1  = (const float*)d_in[4];
  const float* bp1  = (const float*)d_in[5];
  const float* Wp2  = (const float*)d_in[6];
  const float* bp2  = (const float*)d_in[7];
  float* out = (float*)d_out;

  hipLaunchKernelGGL(tnn_scan, dim3(1024), dim3(64), 0, stream,
                     in, caps, Wg, bg, Wp1, bp1, Wp2, bp2, out);
}